// Round 10
// baseline (660.597 us; speedup 1.0000x reference)
//
#include <hip/hip_runtime.h>

// ---------------------------------------------------------------------------
// PiNet: 2x GCNConv + a2^T a2 readout + linear + softmax
// N=100000, E=3200000, D0=128, D1=D2=64, OUT=10
// R9: (1) agg_csr with 8 edge slots x 8 lanes x 2 float4 (2x MLP per wave);
//     (2) BSH 8->7: 782 buckets for 2x build parallelism;
//     (3) outer product readout: deterministic two-phase (no atomics/memset);
//     (4) final linear+softmax: wave-per-output shuffle reduce.
// ---------------------------------------------------------------------------

#define CHUNK 4096   // edges per partition block
#define BSH   7      // bucket = dst >> 7 (128 nodes/bucket)
#define BMASK 127

// Pass A: per-block bucket histogram (LDS atomics only).
__global__ __launch_bounds__(256) void hist_pass(const int* __restrict__ dst,
                                                 int* __restrict__ ghist,
                                                 int E, int nblk, int nbuck) {
    __shared__ int lcnt[1024];
    const int blk = blockIdx.x;
    for (int i = threadIdx.x; i < nbuck; i += 256) lcnt[i] = 0;
    __syncthreads();
    const int base = blk * CHUNK;
    const int end  = min(base + CHUNK, E);
    for (int e = base + threadIdx.x; e < end; e += 256) {
        int d = __builtin_nontemporal_load(&dst[e]);
        atomicAdd(&lcnt[d >> BSH], 1);
    }
    __syncthreads();
    for (int b = threadIdx.x; b < nbuck; b += 256)
        ghist[(size_t)b * nblk + blk] = lcnt[b];
}

// Pass S1: per-bucket exclusive scan over blocks (in place) + bucket total.
__global__ __launch_bounds__(256) void scan_blocks(int* __restrict__ ghist,
                                                   int* __restrict__ btot, int nblk) {
    __shared__ int sh[256];
    int* g = ghist + (size_t)blockIdx.x * nblk;
    const int tid = threadIdx.x;
    int carry = 0;
    for (int base = 0; base < nblk; base += 256) {
        int i = base + tid;
        int v = (i < nblk) ? g[i] : 0;
        sh[tid] = v;
        __syncthreads();
        for (int off = 1; off < 256; off <<= 1) {
            int t = (tid >= off) ? sh[tid - off] : 0;
            __syncthreads();
            sh[tid] += t;
            __syncthreads();
        }
        if (i < nblk) g[i] = carry + sh[tid] - v;  // exclusive + carry
        int tot = sh[255];
        __syncthreads();
        carry += tot;
    }
    if (tid == 0) btot[blockIdx.x] = carry;
}

// Pass S2: exclusive scan of bucket totals -> bstart. nbuck <= 1024.
__global__ void scan_bstart(const int* __restrict__ btot, int* __restrict__ bstart, int nb) {
    __shared__ int sh[1024];
    const int tid = threadIdx.x;
    int v = (tid < nb) ? btot[tid] : 0;
    sh[tid] = v;
    __syncthreads();
    for (int off = 1; off < 1024; off <<= 1) {
        int t = (tid >= off) ? sh[tid - off] : 0;
        __syncthreads();
        sh[tid] += t;
        __syncthreads();
    }
    if (tid < nb) bstart[tid] = sh[tid] - v;
}

// Pass B: place edges into bucket-contiguous bedges (LDS atomics only).
__global__ __launch_bounds__(256) void place_pass(const int* __restrict__ src,
                                                  const int* __restrict__ dst,
                                                  const int* __restrict__ ghist,
                                                  const int* __restrict__ bstart,
                                                  uint2* __restrict__ bedges,
                                                  int E, int nblk, int nbuck) {
    __shared__ int off[1024];
    const int blk = blockIdx.x;
    for (int b = threadIdx.x; b < nbuck; b += 256)
        off[b] = bstart[b] + ghist[(size_t)b * nblk + blk];
    __syncthreads();
    const int base = blk * CHUNK;
    const int end  = min(base + CHUNK, E);
    for (int e = base + threadIdx.x; e < end; e += 256) {
        int d = __builtin_nontemporal_load(&dst[e]);
        int s = __builtin_nontemporal_load(&src[e]);
        int pos = atomicAdd(&off[d >> BSH], 1);
        bedges[pos] = make_uint2((unsigned)s, (unsigned)(d & BMASK));
    }
}

// Pass C: per-bucket counting sort -> ssorted + rowptr/rowend/dinv.
__global__ __launch_bounds__(256) void bucket_csr(const uint2* __restrict__ bedges,
                                                  const int* __restrict__ btot,
                                                  const int* __restrict__ bstart,
                                                  float* __restrict__ dinv,
                                                  int* __restrict__ rowptr,
                                                  int* __restrict__ rowend,
                                                  int* __restrict__ ssorted, int N) {
    __shared__ int lcnt[128];
    __shared__ int sc[128];
    __shared__ int lcur[128];
    const int b   = blockIdx.x;
    const int tid = threadIdx.x;
    const int cnt  = btot[b];
    const int base = bstart[b];
    if (tid < 128) lcnt[tid] = 0;
    __syncthreads();
    for (int i = tid; i < cnt; i += 256)
        atomicAdd(&lcnt[(int)__builtin_nontemporal_load((const unsigned*)&bedges[base + i].y)], 1);
    __syncthreads();
    int c = (tid < 128) ? lcnt[tid] : 0;
    if (tid < 128) sc[tid] = c;
    __syncthreads();
    for (int off = 1; off < 128; off <<= 1) {
        int t = (tid >= off && tid < 128) ? sc[tid - off] : 0;
        __syncthreads();
        if (tid < 128) sc[tid] += t;
        __syncthreads();
    }
    const int excl = (tid < 128) ? (sc[tid] - c) : 0;
    const int n = (b << BSH) + tid;
    if (tid < 128 && n < N) {
        dinv[n]   = rsqrtf((float)c + 1.0f);  // +1 self-loop
        rowptr[n] = base + excl;
        rowend[n] = base + excl + c;
    }
    if (tid < 128) lcur[tid] = excl;
    __syncthreads();
    for (int i = tid; i < cnt; i += 256) {
        uint2 e = bedges[base + i];
        int pos = atomicAdd(&lcur[(int)e.y], 1);
        ssorted[base + pos] = (int)e.x;
    }
}

// ---------------------------------------------------------------------------
// Register-tiled GEMM with dinv epilogue: H[n][c] = dinv[n] * sum_k A[n][k]*W[k][c]
// ---------------------------------------------------------------------------
template <int K>
__global__ __launch_bounds__(256) void gemm_tiled(const float* __restrict__ A,
                                                  const float* __restrict__ W,
                                                  const float* __restrict__ dinv,
                                                  float* __restrict__ H, int N) {
    constexpr int KC = 32;
    __shared__ float xs[64][KC + 4];
    __shared__ float ws[KC][64];
    const int tid  = threadIdx.x;
    const int tx   = tid & 15;
    const int ty   = tid >> 4;
    const int base = blockIdx.x * 64;

    float acc[4][4] = {{0.f}};

    for (int kc = 0; kc < K; kc += KC) {
        for (int idx = tid; idx < 512; idx += 256) {
            int node = idx >> 3, k4 = idx & 7;
            int n = base + node;
            float4 v = make_float4(0.f, 0.f, 0.f, 0.f);
            if (n < N) v = *(const float4*)&A[(long long)n * K + kc + k4 * 4];
            *(float4*)&xs[node][k4 * 4] = v;
        }
        for (int idx = tid; idx < 512; idx += 256) {
            int k = idx >> 4, c4 = idx & 15;
            *(float4*)&ws[k][c4 * 4] = *(const float4*)&W[(long long)(kc + k) * 64 + c4 * 4];
        }
        __syncthreads();

#pragma unroll
        for (int k = 0; k < KC; k += 4) {
            float4 xv[4], wv[4];
#pragma unroll
            for (int i = 0; i < 4; ++i) xv[i] = *(const float4*)&xs[ty * 4 + i][k];
#pragma unroll
            for (int j = 0; j < 4; ++j) wv[j] = *(const float4*)&ws[k + j][tx * 4];
#pragma unroll
            for (int i = 0; i < 4; ++i) {
                float xi[4] = {xv[i].x, xv[i].y, xv[i].z, xv[i].w};
#pragma unroll
                for (int j = 0; j < 4; ++j) {
                    acc[i][0] += xi[j] * wv[j].x;
                    acc[i][1] += xi[j] * wv[j].y;
                    acc[i][2] += xi[j] * wv[j].z;
                    acc[i][3] += xi[j] * wv[j].w;
                }
            }
        }
        __syncthreads();
    }

#pragma unroll
    for (int i = 0; i < 4; ++i) {
        int n = base + ty * 4 + i;
        if (n < N) {
            float d = dinv[n];
            float4 r = make_float4(d * acc[i][0], d * acc[i][1], d * acc[i][2], d * acc[i][3]);
            *(float4*)&H[(long long)n * 64 + tx * 4] = r;
        }
    }
}

// CSR aggregation, fused bias + self-loop. One wave per node.
// 8 edge slots x 8 lanes; each lane loads 2 float4s of the 256B row (2x MLP).
// H is pre-scaled by dinv: out[n] = bias + dinv[n] * (H[n] + sum_s H[s]).
__global__ void agg_csr(const int* __restrict__ rowptr, const int* __restrict__ endptr,
                        const int* __restrict__ ssorted, const float* __restrict__ dinv,
                        const float* __restrict__ H, const float* __restrict__ bias,
                        float* __restrict__ out, int N) {
    const int wid  = (int)(((long long)blockIdx.x * blockDim.x + threadIdx.x) >> 6);
    if (wid >= N) return;
    const int lane = threadIdx.x & 63;
    const int g    = lane >> 3;   // edge slot 0..7
    const int fl   = lane & 7;    // float4 pair index
    const float4* __restrict__ Hv = (const float4*)H;

    const int n   = wid;
    const int beg = rowptr[n];
    const int end = endptr[n];

    float4 a0 = make_float4(0.f, 0.f, 0.f, 0.f);
    float4 a1 = make_float4(0.f, 0.f, 0.f, 0.f);
    for (int e = beg + g; e < end; e += 8) {
        int    s  = __builtin_nontemporal_load(&ssorted[e]);
        float4 h0 = Hv[(long long)s * 16 + fl];
        float4 h1 = Hv[(long long)s * 16 + fl + 8];
        a0.x += h0.x; a0.y += h0.y; a0.z += h0.z; a0.w += h0.w;
        a1.x += h1.x; a1.y += h1.y; a1.z += h1.z; a1.w += h1.w;
    }
    // reduce across the 8 edge slots (lanes differing in bits 3,4,5)
#pragma unroll
    for (int m = 8; m <= 32; m <<= 1) {
        a0.x += __shfl_xor(a0.x, m); a0.y += __shfl_xor(a0.y, m);
        a0.z += __shfl_xor(a0.z, m); a0.w += __shfl_xor(a0.w, m);
        a1.x += __shfl_xor(a1.x, m); a1.y += __shfl_xor(a1.y, m);
        a1.z += __shfl_xor(a1.z, m); a1.w += __shfl_xor(a1.w, m);
    }

    if (g == 0) {
        float  dn = dinv[n];
        float4 s0 = Hv[(long long)n * 16 + fl];
        float4 s1 = Hv[(long long)n * 16 + fl + 8];
        float4 b0 = ((const float4*)bias)[fl];
        float4 b1 = ((const float4*)bias)[fl + 8];
        float4 r0, r1;
        r0.x = b0.x + dn * (s0.x + a0.x); r0.y = b0.y + dn * (s0.y + a0.y);
        r0.z = b0.z + dn * (s0.z + a0.z); r0.w = b0.w + dn * (s0.w + a0.w);
        r1.x = b1.x + dn * (s1.x + a1.x); r1.y = b1.y + dn * (s1.y + a1.y);
        r1.z = b1.z + dn * (s1.z + a1.z); r1.w = b1.w + dn * (s1.w + a1.w);
        ((float4*)out)[(long long)n * 16 + fl]     = r0;
        ((float4*)out)[(long long)n * 16 + fl + 8] = r1;
    }
}

// Readout phase 1: per-block partial h64 (no atomics).
__global__ __launch_bounds__(256) void outer_partial(const float* __restrict__ A2,
                                                     float* __restrict__ partial, int N) {
    __shared__ float rows[8][64];
    const int tid = threadIdx.x;
    const int col = tid & 63;
    const int rg  = tid >> 6;
    float acc[16];
#pragma unroll
    for (int i = 0; i < 16; ++i) acc[i] = 0.f;

    int npb   = (N + gridDim.x - 1) / gridDim.x;
    int start = blockIdx.x * npb;
    int end   = min(start + npb, N);
    for (int nb = start; nb < end; nb += 8) {
        int cnt = min(8, end - nb);
        __syncthreads();
        for (int idx = tid; idx < cnt * 64; idx += 256)
            rows[idx >> 6][idx & 63] = A2[(long long)(nb + (idx >> 6)) * 64 + (idx & 63)];
        __syncthreads();
        for (int r = 0; r < cnt; ++r) {
            float vc = rows[r][col];
#pragma unroll
            for (int i = 0; i < 16; ++i)
                acc[i] += rows[r][rg * 16 + i] * vc;
        }
    }
    float* p = partial + (size_t)blockIdx.x * 4096;
#pragma unroll
    for (int i = 0; i < 16; ++i)
        p[(rg * 16 + i) * 64 + col] = acc[i];
}

// Readout phase 2: sum partials -> h64.
__global__ void outer_final(const float* __restrict__ partial, float* __restrict__ h64, int nblk) {
    int idx = blockIdx.x * blockDim.x + threadIdx.x;  // 0..4095
    float s = 0.f;
    for (int b = 0; b < nblk; ++b) s += partial[(size_t)b * 4096 + idx];
    h64[idx] = s;
}

// o = h64.flat @ Wl + bl ; softmax -> out[10]. 10 waves, one output each.
__global__ void final_kernel(const float* __restrict__ h64, const float* __restrict__ Wl,
                             const float* __restrict__ bl, float* __restrict__ out) {
    __shared__ float o[10];
    const int w    = threadIdx.x >> 6;
    const int lane = threadIdx.x & 63;
    float acc = 0.f;
    for (int i = lane; i < 4096; i += 64) acc += h64[i] * Wl[i * 10 + w];
#pragma unroll
    for (int m = 1; m < 64; m <<= 1) acc += __shfl_xor(acc, m);
    if (lane == 0) o[w] = acc + bl[w];
    __syncthreads();
    if (threadIdx.x == 0) {
        float mx = o[0];
        for (int k = 1; k < 10; ++k) mx = fmaxf(mx, o[k]);
        float s = 0.f, e[10];
        for (int k = 0; k < 10; ++k) { e[k] = expf(o[k] - mx); s += e[k]; }
        for (int k = 0; k < 10; ++k) out[k] = e[k] / s;
    }
}

extern "C" void kernel_launch(void* const* d_in, const int* in_sizes, int n_in,
                              void* d_out, int out_size, void* d_ws, size_t ws_size,
                              hipStream_t stream) {
    const float* x   = (const float*)d_in[0];
    const int*   ei  = (const int*)d_in[1];
    const float* Wa1 = (const float*)d_in[2];
    const float* ba1 = (const float*)d_in[3];
    const float* Wa2 = (const float*)d_in[4];
    const float* ba2 = (const float*)d_in[5];
    const float* Wl  = (const float*)d_in[6];
    const float* bl  = (const float*)d_in[7];
    float* out = (float*)d_out;

    const int N = in_sizes[0] / 128;
    const int E = in_sizes[1] / 2;
    const int* src = ei;
    const int* dst = ei + E;

    const int nblk  = (E + CHUNK - 1) / CHUNK;        // 782
    const int nbuck = (N + BMASK) >> BSH;             // 782 (<= 1024)

    // --- workspace layout ---
    // region0 (union, 51.2MB): bufH+bufA | bedges(25.6MB)+ghist(2.5MB)+btot+bstart
    // partial (4MB for outer_partial) aliases bufH (dead after agg2).
    char* wsb = (char*)d_ws;
    float* bufH   = (float*)wsb;
    float* bufA   = bufH + (size_t)N * 64;
    float* partial= bufH;                                  // reused after agg2
    uint2* bedges = (uint2*)wsb;                           // [E]
    int*   ghist  = (int*)(wsb + (size_t)E * 8);           // [nbuck*nblk]
    int*   btot   = ghist + (size_t)nbuck * nblk;          // [1024]
    int*   bstart = btot + 1024;                           // [1024]
    char*  tail   = wsb + (size_t)N * 128 * 4;             // 51.2MB
    float* dinv   = (float*)tail;               tail += (size_t)N * 4;
    float* h64    = (float*)tail;               tail += 4096 * 4;
    int*   rowptr = (int*)tail;                 tail += (size_t)N * 4;
    int*   rowend = (int*)tail;                 tail += (size_t)N * 4;
    int*   ssorted= (int*)tail;                 tail += (size_t)E * 4;

    // --- CSR build (no global atomics) ---
    hist_pass<<<nblk, 256, 0, stream>>>(dst, ghist, E, nblk, nbuck);
    scan_blocks<<<nbuck, 256, 0, stream>>>(ghist, btot, nblk);
    scan_bstart<<<1, 1024, 0, stream>>>(btot, bstart, nbuck);
    place_pass<<<nblk, 256, 0, stream>>>(src, dst, ghist, bstart, bedges, E, nblk, nbuck);
    bucket_csr<<<nbuck, 256, 0, stream>>>(bedges, btot, bstart, dinv, rowptr, rowend, ssorted, N);

    // --- layer 1 ---
    gemm_tiled<128><<<(N + 63) / 64, 256, 0, stream>>>(x, Wa1, dinv, bufH, N);
    agg_csr<<<(N + 3) / 4, 256, 0, stream>>>(rowptr, rowend, ssorted, dinv, bufH, ba1, bufA, N);

    // --- layer 2 ---
    gemm_tiled<64><<<(N + 63) / 64, 256, 0, stream>>>(bufA, Wa2, dinv, bufH, N);
    agg_csr<<<(N + 3) / 4, 256, 0, stream>>>(rowptr, rowend, ssorted, dinv, bufH, ba2, bufA, N);

    // --- readout (deterministic two-phase) ---
    outer_partial<<<256, 256, 0, stream>>>(bufA, partial, N);
    outer_final<<<16, 256, 0, stream>>>(partial, h64, 256);
    final_kernel<<<1, 640, 0, stream>>>(h64, Wl, bl, out);
}